// Round 1
// 8301.544 us; speedup vs baseline: 1.1122x; 1.1122x over previous
//
#include <hip/hip_runtime.h>
#include <cstdint>
#include <cstddef>

#define PL 4
#define LL 12
#define NMAT 16
#define BB 16
#define SEQ 197
#define DS 384
#define DT 768
#define HEADS 12
#define MR 3152           // BB*SEQ
#define KS 96             // subspace rank
#define PD 144            // oversampled subspace dim
#define EPSR 1e-4f
#define CLAMPF 0.99999988f   // fp32(1 - 1e-7)

#define TLDA 148          // full-storage row stride for PD (4*37: quads sweep all bank groups)
#define SLDA 100          // full-storage row stride for KS (4*25)

typedef long long i64;

// ---------------- small device helpers ----------------
__device__ __forceinline__ float hash01(uint32_t x){
  x ^= x >> 16; x *= 0x7feb352dU; x ^= x >> 15; x *= 0x846ca68bU; x ^= x >> 16;
  return (float)(x & 0xFFFFFFu) * (1.0f/8388608.0f) - 1.0f;   // [-1,1)
}
__device__ __forceinline__ float block_sum256(float v, float* red){
  for (int o = 32; o > 0; o >>= 1) v += __shfl_down(v, o);
  int t = threadIdx.x;
  if ((t & 63) == 0) red[t >> 6] = v;
  __syncthreads();
  float r = red[0] + red[1] + red[2] + red[3];
  __syncthreads();
  return r;
}
__device__ __forceinline__ float block_min256(float v, float* red){
  for (int o = 32; o > 0; o >>= 1) v = fminf(v, __shfl_down(v, o));
  int t = threadIdx.x;
  if ((t & 63) == 0) red[t >> 6] = v;
  __syncthreads();
  float r = fminf(fminf(red[0], red[1]), fminf(red[2], red[3]));
  __syncthreads();
  return r;
}
__device__ __forceinline__ float block_max256(float v, float* red){
  for (int o = 32; o > 0; o >>= 1) v = fmaxf(v, __shfl_down(v, o));
  int t = threadIdx.x;
  if ((t & 63) == 0) red[t >> 6] = v;
  __syncthreads();
  float r = fmaxf(fmaxf(red[0], red[1]), fmaxf(red[2], red[3]));
  __syncthreads();
  return r;
}
__device__ __forceinline__ int prow(int idx){   // row of packed-lower index
  int i = (int)((sqrtf(8.0f*(float)idx + 1.0f) - 1.0f)*0.5f);
  while ((i+1)*(i+2)/2 <= idx) i++;
  while (i*(i+1)/2 > idx) i--;
  return i;
}
__device__ __forceinline__ float gpiv(float q, float pm){
  return (fabsf(q) < pm) ? ((q < 0.f) ? -pm : pm) : q;
}
__device__ __forceinline__ float clampx(float x){
  return fminf(fmaxf(x, -1e15f), 1e15f);
}
__device__ __forceinline__ int sturm_count(const float* d, const float* e, int n, float x, float pm){
  float q = d[0] - x; int cnt = (q < 0.f) ? 1 : 0;
  for (int i = 1; i < n; i++){
    q = gpiv(q, pm);
    q = (d[i] - x) - e[i-1]*e[i-1]/q;
    cnt += (q < 0.f) ? 1 : 0;
  }
  return cnt;
}

// ---------------- Z = tokens @ proj^T  (NT gemm, 64x128x16) ----------------
__global__ __launch_bounds__(256) void k_zgemm(const float* __restrict__ A,
                                               const float* __restrict__ Pm,
                                               float* __restrict__ Z, int Kdim)
{
  __shared__ float As[16][68];
  __shared__ float Bs[16][132];
  const int t = threadIdx.x;
  const int bm = blockIdx.y * 64;
  const int bn = blockIdx.x * 128;
  const int tm = t >> 5;     // 0..7  -> rows tm*8..
  const int tn = t & 31;     // 0..31 -> cols tn*4..
  float acc[8][4];
#pragma unroll
  for (int i = 0; i < 8; i++)
#pragma unroll
    for (int j = 0; j < 4; j++) acc[i][j] = 0.f;

  for (int k0 = 0; k0 < Kdim; k0 += 16){
#pragma unroll
    for (int r = 0; r < 4; r++){
      int idx = t + r*256; int kk = idx & 15; int m = idx >> 4;
      As[kk][m] = A[(size_t)(bm+m)*Kdim + k0 + kk];
    }
#pragma unroll
    for (int r = 0; r < 8; r++){
      int idx = t + r*256; int kk = idx & 15; int n = idx >> 4;
      Bs[kk][n] = Pm[(size_t)(bn+n)*Kdim + k0 + kk];
    }
    __syncthreads();
#pragma unroll
    for (int kk = 0; kk < 16; kk++){
      float a[8], b[4];
#pragma unroll
      for (int i = 0; i < 8; i++) a[i] = As[kk][tm*8+i];
#pragma unroll
      for (int j = 0; j < 4; j++) b[j] = Bs[kk][tn*4+j];
#pragma unroll
      for (int i = 0; i < 8; i++)
#pragma unroll
        for (int j = 0; j < 4; j++) acc[i][j] += a[i]*b[j];
    }
    __syncthreads();
  }
#pragma unroll
  for (int i = 0; i < 8; i++){
    int row = bm + tm*8 + i;
#pragma unroll
    for (int j = 0; j < 4; j++)
      Z[(size_t)row*DS + bn + tn*4 + j] = acc[i][j];
  }
}

// ---------------- column sums of Z (for mean) ----------------
__global__ __launch_bounds__(256) void k_mu(const float* __restrict__ Z,
                                            float* __restrict__ mu, int mat0)
{
  int r0 = blockIdx.x * 16;
  int mat = mat0 + r0 / MR;     // 16-row blocks never straddle a layer (3152 % 16 == 0)
  int t = threadIdx.x;
  for (int c = t; c < DS; c += 256){
    float s = 0.f;
    for (int r = 0; r < 16; r++) s += Z[(size_t)(r0+r)*DS + c];
    unsafeAtomicAdd(&mu[mat*DS + c], s);
  }
}

// ---------------- G += Z^T Z partial (64x128 tile, k-split 8, atomic) ----------------
__global__ __launch_bounds__(256) void k_cov(const float* __restrict__ Z,
                                             float* __restrict__ Gacc, int baseBatch)
{
  __shared__ float As[16][68];
  __shared__ float Bs[16][132];
  int bz = blockIdx.z; int b = bz >> 3; int ks = bz & 7;
  int k0s = ks * 394, k1 = k0s + 394;     // 3152 = 8*394
  const float* Zb = Z + (size_t)b * MR * DS;
  int bi = blockIdx.y * 64, bj = blockIdx.x * 128;
  int t = threadIdx.x; int tm = t >> 5, tn = t & 31;
  float acc[8][4];
#pragma unroll
  for (int i = 0; i < 8; i++)
#pragma unroll
    for (int j = 0; j < 4; j++) acc[i][j] = 0.f;

  for (int k0 = k0s; k0 < k1; k0 += 16){
#pragma unroll
    for (int r = 0; r < 4; r++){
      int idx = t + r*256; int i = idx & 63; int kk = idx >> 6;
      int krow = k0 + kk;
      As[kk][i] = (krow < k1) ? Zb[(size_t)krow*DS + bi + i] : 0.f;
    }
#pragma unroll
    for (int r = 0; r < 8; r++){
      int idx = t + r*256; int j = idx & 127; int kk = idx >> 7;
      int krow = k0 + kk;
      Bs[kk][j] = (krow < k1) ? Zb[(size_t)krow*DS + bj + j] : 0.f;
    }
    __syncthreads();
#pragma unroll
    for (int kk = 0; kk < 16; kk++){
      float a[8], b[4];
#pragma unroll
      for (int i = 0; i < 8; i++) a[i] = As[kk][tm*8+i];
#pragma unroll
      for (int j = 0; j < 4; j++) b[j] = Bs[kk][tn*4+j];
#pragma unroll
      for (int i = 0; i < 8; i++)
#pragma unroll
        for (int j = 0; j < 4; j++) acc[i][j] += a[i]*b[j];
    }
    __syncthreads();
  }
  float* Gb = Gacc + (size_t)(baseBatch+b)*DS*DS;
#pragma unroll
  for (int i = 0; i < 8; i++){
    int row = bi + tm*8 + i;
#pragma unroll
    for (int j = 0; j < 4; j++)
      unsafeAtomicAdd(&Gb[(size_t)row*DS + bj + tn*4 + j], acc[i][j]);
  }
}

// ---------------- C = G/M - mu mu^T / M^2 + eps I ----------------
__global__ __launch_bounds__(256) void k_cov_epi(float* __restrict__ C, const float* __restrict__ mu)
{
  const float invM = 1.0f / (float)MR;
  size_t idx = (size_t)blockIdx.x * 256 + threadIdx.x;
  size_t total = (size_t)NMAT * DS * DS;
  if (idx >= total) return;
  int b = (int)(idx / (DS*DS));
  int rem = (int)(idx % (DS*DS));
  int r = rem / DS, c = rem % DS;
  float m1 = mu[b*DS + r] * invM;
  float m2 = mu[b*DS + c] * invM;
  float v = C[idx]*invM - m1*m2 + ((r == c) ? EPSR : 0.f);
  C[idx] = v;
}

// ---------------- power iteration -> u = 0.67 * lambda_max ----------------
__global__ __launch_bounds__(384) void k_lmax(const float* __restrict__ C, float* __restrict__ u_out)
{
  __shared__ float v[DS], w[DS], red[DS];
  int b = blockIdx.x, t = threadIdx.x;
  const float* Cb = C + (size_t)b*DS*DS;
  v[t] = hash01((uint32_t)(t*2654435761u + 12345u)) + 0.01f;
  __syncthreads();
  float lam = 1.0f;
  for (int it = 0; it < 16; it++){
    float s = 0.f;
    const float* row = Cb + (size_t)t*DS;
    for (int j = 0; j < DS; j++) s += row[j]*v[j];
    w[t] = s;
    __syncthreads();
    red[t] = s*s;
    __syncthreads();
    if (t < 128) red[t] += red[t+256];
    __syncthreads();
    for (int st = 128; st > 0; st >>= 1){
      if (t < st) red[t] += red[t+st];
      __syncthreads();
    }
    float nrm = sqrtf(fmaxf(red[0], 1e-30f));
    lam = nrm;
    v[t] = w[t] / nrm;
    __syncthreads();
  }
  if (t == 0) u_out[b] = 0.67f * lam;
}

// ---------------- fill Omega ----------------
__global__ __launch_bounds__(256) void k_omega(float* __restrict__ W)
{
  int idx = blockIdx.x*256 + threadIdx.x;   // grid sized exactly
  W[idx] = hash01((uint32_t)idx * 2246822519u + 374761393u);
}

// ---------------- batched NN gemm 64x48x16 with Chebyshev epilogue ----------------
// mode 0: out = acc ; mode 1: out = (2/u)acc - prev ; mode 2: out = (4/u)acc - 2*tj - prev
__global__ __launch_bounds__(256) void k_cheb(const float* __restrict__ A, int lda, i64 aBS,
                                              const float* __restrict__ Bm, int ldb, i64 bBS,
                                              float* __restrict__ out, i64 oBS,
                                              const float* __restrict__ tj,
                                              const float* __restrict__ prev,
                                              const float* __restrict__ u_arr,
                                              int Kdim, int Ncols, int mode)
{
  __shared__ float As[16][68];
  __shared__ float Bs[16][52];
  int b = blockIdx.z;
  const float* Ab = A + (size_t)b*aBS;
  const float* Bb = Bm + (size_t)b*bBS;
  int bm = blockIdx.y*64, bn = blockIdx.x*48;
  int t = threadIdx.x, tm = t >> 4, tn = t & 15;
  float acc[4][3];
#pragma unroll
  for (int i = 0; i < 4; i++)
#pragma unroll
    for (int j = 0; j < 3; j++) acc[i][j] = 0.f;

  for (int k0 = 0; k0 < Kdim; k0 += 16){
#pragma unroll
    for (int r = 0; r < 4; r++){
      int idx = t + r*256; int kk = idx & 15; int m = idx >> 4;
      As[kk][m] = Ab[(size_t)(bm+m)*lda + k0 + kk];
    }
#pragma unroll
    for (int r = 0; r < 3; r++){
      int idx = t + r*256; int n = idx % 48; int kk = idx / 48;
      Bs[kk][n] = Bb[(size_t)(k0+kk)*ldb + bn + n];
    }
    __syncthreads();
#pragma unroll
    for (int kk = 0; kk < 16; kk++){
      float a[4], bv[3];
#pragma unroll
      for (int i = 0; i < 4; i++) a[i] = As[kk][tm*4+i];
#pragma unroll
      for (int j = 0; j < 3; j++) bv[j] = Bs[kk][tn*3+j];
#pragma unroll
      for (int i = 0; i < 4; i++)
#pragma unroll
        for (int j = 0; j < 3; j++) acc[i][j] += a[i]*bv[j];
    }
    __syncthreads();
  }
  float uu = (mode == 0) ? 1.f : u_arr[b];
#pragma unroll
  for (int i = 0; i < 4; i++){
    int row = bm + tm*4 + i;
#pragma unroll
    for (int j = 0; j < 3; j++){
      int col = bn + tn*3 + j;
      size_t oidx = (size_t)b*oBS + (size_t)row*Ncols + col;
      float r;
      if (mode == 0)       r = acc[i][j];
      else if (mode == 1)  r = (2.f/uu)*acc[i][j] - prev[oidx];
      else                 r = (4.f/uu)*acc[i][j] - 2.f*tj[oidx] - prev[oidx];
      out[oidx] = r;
    }
  }
}

// ---------------- batched TN gemm 48x48x16 : out[b] = A_b^T B_b ----------------
__global__ __launch_bounds__(256) void k_tn(const float* __restrict__ A, i64 aBS,
                                            const float* __restrict__ Bm, i64 bBS,
                                            float* __restrict__ out, i64 oBS,
                                            int Mdim, int Kdim, int pairMode)
{
  __shared__ float As[16][52], Bs[16][52];
  int b = blockIdx.z;
  const float *Ab, *Bb;
  if (pairMode){ int p = b/12, l = b%12; Ab = A + (size_t)(12+p)*aBS; Bb = Bm + (size_t)l*bBS; }
  else         { Ab = A + (size_t)b*aBS; Bb = Bm + (size_t)b*bBS; }
  int bi = blockIdx.y*48, bj = blockIdx.x*48;
  int t = threadIdx.x, tm = t >> 4, tn = t & 15;
  float acc[3][3];
#pragma unroll
  for (int i = 0; i < 3; i++)
#pragma unroll
    for (int j = 0; j < 3; j++) acc[i][j] = 0.f;

  for (int k0 = 0; k0 < Kdim; k0 += 16){
#pragma unroll
    for (int r = 0; r < 3; r++){
      int idx = t + r*256; int m = idx % 48; int kk = idx / 48;
      As[kk][m] = Ab[(size_t)(k0+kk)*Mdim + bi + m];
    }
#pragma unroll
    for (int r = 0; r < 3; r++){
      int idx = t + r*256; int n = idx % 48; int kk = idx / 48;
      Bs[kk][n] = Bb[(size_t)(k0+kk)*Mdim + bj + n];
    }
    __syncthreads();
#pragma unroll
    for (int kk = 0; kk < 16; kk++){
      float a[3], bv[3];
#pragma unroll
      for (int i = 0; i < 3; i++) a[i] = As[kk][tm*3+i];
#pragma unroll
      for (int j = 0; j < 3; j++) bv[j] = Bs[kk][tn*3+j];
#pragma unroll
      for (int i = 0; i < 3; i++)
#pragma unroll
        for (int j = 0; j < 3; j++) acc[i][j] += a[i]*bv[j];
    }
    __syncthreads();
  }
#pragma unroll
  for (int i = 0; i < 3; i++)
#pragma unroll
    for (int j = 0; j < 3; j++)
      out[(size_t)b*oBS + (size_t)(bi+tm*3+i)*Mdim + bj + tn*3 + j] = acc[i][j];
}

// ---------------- Cholesky of scaled Gram (packed lower, LDS), per-batch ----------------
__global__ __launch_bounds__(256) void k_chol(const float* __restrict__ G, i64 gBS,
                                              float* __restrict__ Rout, i64 rBS,
                                              int n, float ridge)
{
  __shared__ float Cp[PD*(PD+1)/2];
  __shared__ float dinv[PD];
  int b = blockIdx.x, t = threadIdx.x;
  const float* Gb = G + (size_t)b*gBS;
  int pcount = n*(n+1)/2;
  for (int j = t; j < n; j += 256) dinv[j] = rsqrtf(fmaxf(Gb[(size_t)j*n+j], 1e-30f));
  __syncthreads();
  for (int idx = t; idx < pcount; idx += 256){
    int i = prow(idx); int j = idx - i*(i+1)/2;
    float g = Gb[(size_t)i*n+j]*dinv[i]*dinv[j];
    if (i == j) g += ridge;
    Cp[idx] = g;
  }
  __syncthreads();
  for (int j = 0; j < n; j++){
    int dj = j*(j+1)/2 + j;
    if (t == 0){
      float s = Cp[dj];
      Cp[dj] = (s > 1e-9f) ? sqrtf(s) : 1e12f;   // deflate junk directions
    }
    __syncthreads();
    float Ljj = Cp[dj];
    for (int i = j+1+t; i < n; i += 256) Cp[i*(i+1)/2+j] /= Ljj;
    __syncthreads();
    for (int i = j+1+t; i < n; i += 256){
      int bi2 = i*(i+1)/2;
      float Lij = Cp[bi2+j];
      for (int c = j+1; c <= i; c++) Cp[bi2+c] -= Lij * Cp[c*(c+1)/2+j];
    }
    __syncthreads();
  }
  float* Rb = Rout + (size_t)b*rBS;
  for (int idx = t; idx < pcount; idx += 256) Rb[idx] = Cp[idx];
  for (int j = t; j < n; j += 256) Rb[pcount+j] = dinv[j];
}

// ---------------- W <- W * R^-1 (row-wise forward substitution) ----------------
__global__ __launch_bounds__(64) void k_trisolve(float* __restrict__ W, i64 wBS, int rowsPerBatch,
                                                 const float* __restrict__ Rp, i64 rBS, int n)
{
  __shared__ float rowb[64][145];
  int t = threadIdx.x;
  int grow = blockIdx.x*64 + t;
  int b = grow / rowsPerBatch, r = grow % rowsPerBatch;
  const float* Lb = Rp + (size_t)b*rBS;
  const float* dinv = Lb + n*(n+1)/2;
  float* Wrow = W + (size_t)b*wBS + (size_t)r*n;
  for (int j = 0; j < n; j++) rowb[t][j] = Wrow[j]*dinv[j];
  for (int j = 0; j < n; j++){
    int base = j*(j+1)/2;
    float s = rowb[t][j];
    for (int i = 0; i < j; i++) s -= Lb[base+i]*rowb[t][i];
    rowb[t][j] = s / Lb[base+j];
  }
  for (int j = 0; j < n; j++) Wrow[j] = rowb[t][j];
}

// ---------------- Householder tridiagonalization, FULL symmetric storage ----------------
// A: n x lda in LDS, symmetric, lda multiple of 4 (rows 16B aligned).
// On exit: d/e = tridiagonal, bet = Householder betas, reflector k stored in
// row k, cols k+1..n-1 (first element patched to vfirst). Requires n % 4 == 0.
// Junk note: the 16B-aligned rank-2 update may read/write up to 3 cells with
// col <= k; those cells are never read by sigma/alpha/matvec/dump-consumers
// (all use col >= k+1), and each junk column is touched by <= 3 steps, so
// values stay finite and never leak into live data.
__device__ void tridiag_full(float* A, int n, int lda,
                             float* d, float* e, float* bet,
                             float* w1, float* red)
{
  const int t = threadIdx.x;
  for (int k = 0; k < n-2; k++){
    float* rowk = A + (size_t)k*lda;
    float alpha = rowk[k+1];                 // read before any write this step
    float p = 0.f;
    for (int i = k+2+t; i < n; i += 256){ float x = rowk[i]; p += x*x; }
    float sigma = block_sum256(p, red);      // uniform across block
    float ek, beta, vfirst;
    if (sigma < 1e-28f){ ek = alpha; beta = 0.f; vfirst = 0.f; }
    else {
      float nu = sqrtf(alpha*alpha + sigma);
      ek = (alpha >= 0.f) ? -nu : nu;
      vfirst = alpha - ek;
      beta = 1.f/(nu*(nu + fabsf(alpha)));
    }
    if (t == 0){ d[k] = rowk[k]; e[k] = ek; bet[k] = beta; rowk[k+1] = vfirst; }
    __syncthreads();
    if (beta != 0.f){
      // w1 = beta * A * v   (v = rowk[k+1..n-1]); contiguous vectorized rows
      for (int i = k+1+t; i < n; i += 256){
        const float* rowi = A + (size_t)i*lda;
        float s = 0.f;
        int j = k+1;
        int j1 = (k+4) & ~3; if (j1 > n) j1 = n;   // scalar head to 16B boundary
        for (; j < j1; j++) s += rowi[j]*rowk[j];
#pragma unroll 4
        for (; j < n; j += 4){
          float4 a4 = *(const float4*)(rowi + j);
          float4 v4 = *(const float4*)(rowk + j);
          s += a4.x*v4.x + a4.y*v4.y + a4.z*v4.z + a4.w*v4.w;
        }
        w1[i] = beta*s;
      }
      __syncthreads();
      float pp = 0.f;
      for (int i = k+1+t; i < n; i += 256) pp += w1[i]*rowk[i];
      float wv = block_sum256(pp, red);
      float Kw = 0.5f*beta*wv;
      for (int i = k+1+t; i < n; i += 256) w1[i] -= Kw*rowk[i];
      __syncthreads();
      // rank-2 update of the full trailing block (both triangles; fp-exact symmetric)
      int j0 = (k+1) & ~3;                   // aligned start; <=3 junk cols (harmless)
      for (int i = k+1+t; i < n; i += 256){
        float* rowi = A + (size_t)i*lda;
        float vi = rowk[i], wi = w1[i];
#pragma unroll 4
        for (int j = j0; j < n; j += 4){
          float4 a4 = *(float4*)(rowi + j);
          float4 w4 = *(const float4*)(w1 + j);
          float4 v4 = *(const float4*)(rowk + j);
          a4.x -= vi*w4.x + wi*v4.x;
          a4.y -= vi*w4.y + wi*v4.y;
          a4.z -= vi*w4.z + wi*v4.z;
          a4.w -= vi*w4.w + wi*v4.w;
          *(float4*)(rowi + j) = a4;
        }
      }
      __syncthreads();
    }
  }
  if (t == 0){
    int n2 = n-2, n1 = n-1;
    d[n2] = A[(size_t)n2*lda+n2];
    e[n2] = A[(size_t)n1*lda+n2];
    d[n1] = A[(size_t)n1*lda+n1];
    bet[n2] = 0.f; bet[n1] = 0.f; e[n1] = 0.f;
  }
  __syncthreads();
}

// ---------------- tridiagonalize B (144), dump full rows (reflectors) / beta / d,e ----------------
// Dynamic LDS: PD*TLDA + 4*PD + 8 floats (~87.6 KB; gfx950 allows 160 KB/WG).
__global__ __launch_bounds__(256) void k_tridiagB(const float* __restrict__ Bg,
                                                  float* __restrict__ Bh,
                                                  float* __restrict__ betg,
                                                  float* __restrict__ deg)
{
  extern __shared__ float smem[];
  float* A   = smem;                 // PD * TLDA
  float* d   = A   + PD*TLDA;
  float* e   = d   + PD;
  float* bet = e   + PD;
  float* w1  = bet + PD;
  float* red = w1  + PD;             // 8
  int b = blockIdx.x, t = threadIdx.x;
  const float* Bb = Bg + (size_t)b*PD*PD;
  for (int idx = t; idx < PD*PD; idx += 256){
    int i = idx / PD, j = idx - i*PD;
    A[i*TLDA + j] = 0.5f*(Bb[idx] + Bb[j*PD + i]);
  }
  __syncthreads();
  tridiag_full(A, PD, TLDA, d, e, bet, w1, red);
  float* Bhb = Bh + (size_t)b*PD*PD;
  for (int idx = t; idx < PD*PD; idx += 256){
    int i = idx / PD, j = idx - i*PD;
    Bhb[idx] = A[i*TLDA + j];
  }
  for (int i = t; i < PD; i += 256){
    betg[b*PD + i] = bet[i];
    deg[b*2*PD + i] = d[i];
    deg[b*2*PD + PD + i] = e[i];
  }
}

// ---------------- bisection (idx 48..143) + twisted-factorization eigenvectors ----------------
__global__ __launch_bounds__(256) void k_invit(const float* __restrict__ deg, float* __restrict__ Yg)
{
  __shared__ float d[PD], e[PD], lam[KS], red[8];
  __shared__ float bounds[2];
  __shared__ float tw[2][48][PD+1];
  int b = blockIdx.x, t = threadIdx.x;
  for (int i = t; i < PD; i += 256){ d[i] = deg[b*2*PD + i]; e[i] = deg[b*2*PD + PD + i]; }
  __syncthreads();
  float lo = 1e30f, hi = -1e30f;
  for (int i = t; i < PD; i += 256){
    float ea = (i > 0) ? fabsf(e[i-1]) : 0.f;
    float eb = (i < PD-1) ? fabsf(e[i]) : 0.f;
    lo = fminf(lo, d[i]-ea-eb); hi = fmaxf(hi, d[i]+ea+eb);
  }
  lo = block_min256(lo, red);
  hi = block_max256(hi, red);
  if (t == 0){ bounds[0] = lo - 1e-5f; bounds[1] = hi + 1e-5f; }
  __syncthreads();
  const float pm = 1e-12f;
  if (t < KS){
    int target = (PD - KS) + t;
    float a = bounds[0], bb2 = bounds[1];
    for (int it = 0; it < 34; it++){
      float mid = 0.5f*(a+bb2);
      int cnt = sturm_count(d, e, PD, mid, pm);
      if (cnt > target) bb2 = mid; else a = mid;
    }
    lam[t] = 0.5f*(a+bb2);
  }
  __syncthreads();
  if (t == 0){
    float scale = fmaxf(fabsf(lam[0]), fabsf(lam[KS-1])) + 1e-20f;
    int pos = 0;
    for (int v = 1; v < KS; v++){
      if (lam[v] - lam[v-1] < 2e-5f*scale){ pos++; lam[v] += (float)pos*4e-6f*scale; }
      else pos = 0;
    }
  }
  __syncthreads();
  float* Yb = Yg + (size_t)b*PD*KS;
  for (int batch = 0; batch < 2; batch++){
    if (t < 48){
      int v = batch*48 + t;
      float L = lam[v];
      float* pF = tw[0][t];
      float* sb = tw[1][t];
      pF[0] = gpiv(d[0]-L, pm);
      for (int i = 1; i < PD; i++) pF[i] = gpiv((d[i]-L) - e[i-1]*e[i-1]/pF[i-1], pm);
      sb[PD-1] = gpiv(d[PD-1]-L, pm);
      for (int i = PD-2; i >= 0; i--) sb[i] = gpiv((d[i]-L) - e[i]*e[i]/sb[i+1], pm);
      int r = 0; float best = 1e30f;
      for (int i = 0; i < PD; i++){
        float g = fabsf(pF[i] + sb[i] - (d[i]-L));
        if (g < best){ best = g; r = i; }
      }
      pF[r] = 1.f;
      for (int i = r-1; i >= 0; i--){
        float xi = -e[i]*pF[i+1]/pF[i];   // pF[i] still holds pivot
        pF[i] = clampx(xi);
      }
      for (int i = r+1; i < PD; i++){
        float xm1 = (i-1 == r) ? 1.f : sb[i-1];
        float xi = -e[i-1]*xm1/sb[i];
        sb[i] = clampx(xi);
      }
      float nn = 0.f;
      for (int i = 0; i <= r; i++) nn += pF[i]*pF[i];
      for (int i = r+1; i < PD; i++) nn += sb[i]*sb[i];
      float inv = rsqrtf(fmaxf(nn, 1e-30f));
      for (int i = 0; i <= r; i++) Yb[(size_t)i*KS + v] = pF[i]*inv;
      for (int i = r+1; i < PD; i++) Yb[(size_t)i*KS + v] = sb[i]*inv;
    }
    __syncthreads();
  }
}

// ---------------- back-transform Y through stored Householder reflectors ----------------
// Bh now holds full rows: reflector k = Bh[b][k][k+1..PD-1] (coalesced loads).
__global__ __launch_bounds__(256) void k_backxf(const float* __restrict__ Bh,
                                                const float* __restrict__ betg,
                                                float* __restrict__ Yg)
{
  __shared__ float sY[PD][KS+1];
  __shared__ float v1[PD], tf[KS], part[2][KS];
  int b = blockIdx.x, t = threadIdx.x;
  float* Yb = Yg + (size_t)b*PD*KS;
  const float* Bhb = Bh + (size_t)b*PD*PD;
  const float* betb = betg + b*PD;
  for (int idx = t; idx < PD*KS; idx += 256){ sY[idx/KS][idx%KS] = Yb[idx]; }
  __syncthreads();
  for (int k = PD-3; k >= 0; k--){
    float beta = betb[k];
    if (beta == 0.f) continue;
    for (int i = k+1+t; i < PD; i += 256) v1[i] = Bhb[(size_t)k*PD + i];
    __syncthreads();
    int mlen = PD-1-k;
    if (t < 2*KS){
      int c = t % KS, h = t / KS;
      int half = (mlen+1)/2;
      int i0 = k+1 + h*half;
      int i1 = (h == 0) ? (k+1+half) : PD;
      float s = 0.f;
      for (int i = i0; i < i1; i++) s += v1[i]*sY[i][c];
      part[h][c] = s;
    }
    __syncthreads();
    if (t < KS) tf[t] = beta*(part[0][t] + part[1][t]);
    __syncthreads();
    for (int idx = t; idx < mlen*KS; idx += 256){
      int i = k+1 + idx/KS, c = idx % KS;
      sY[i][c] -= v1[i]*tf[c];
    }
    __syncthreads();
  }
  for (int idx = t; idx < PD*KS; idx += 256) Yb[idx] = sY[idx/KS][idx%KS];
}

// ---------------- sigma: eig(G) where G = M^T M precomputed; theta = acos(min(sqrt(L),clamp)) ----------------
__global__ __launch_bounds__(256) void k_sigma(const float* __restrict__ Gg, float* __restrict__ d2g)
{
  __shared__ __align__(16) float A[KS*SLDA];
  __shared__ float d[KS], e[KS], bet[KS], w1[KS], red[8];
  __shared__ float bounds[2];
  int b = blockIdx.x, t = threadIdx.x;
  const float* Gb = Gg + (size_t)b*KS*KS;
  for (int idx = t; idx < KS*KS; idx += 256){
    int i = idx / KS, j = idx - i*KS;
    A[i*SLDA + j] = 0.5f*(Gb[idx] + Gb[(size_t)j*KS + i]);
  }
  __syncthreads();
  tridiag_full(A, KS, SLDA, d, e, bet, w1, red);
  float lo = 1e30f, hi = -1e30f;
  for (int i = t; i < KS; i += 256){
    float ea = (i > 0) ? fabsf(e[i-1]) : 0.f;
    float eb = (i < KS-1) ? fabsf(e[i]) : 0.f;
    lo = fminf(lo, d[i]-ea-eb); hi = fmaxf(hi, d[i]+ea+eb);
  }
  lo = block_min256(lo, red);
  hi = block_max256(hi, red);
  if (t == 0){ bounds[0] = lo - 1e-6f; bounds[1] = hi + 1e-6f; }
  __syncthreads();
  const float pm = 1e-12f;
  float th2 = 0.f;
  if (t < KS){
    float a = bounds[0], bb2 = bounds[1];
    for (int it = 0; it < 34; it++){
      float mid = 0.5f*(a+bb2);
      int cnt = sturm_count(d, e, KS, mid, pm);
      if (cnt > t) bb2 = mid; else a = mid;
    }
    float L = 0.5f*(a+bb2);
    float sig = sqrtf(fmaxf(L, 0.f));
    sig = fminf(sig, CLAMPF);
    float th = acosf(sig);
    th2 = th*th;
  }
  float total = block_sum256(th2, red);
  if (t == 0) d2g[b] = total;
}

// ---------------- weights: softmax(-d2/(k*softplus(lt))) over layers ----------------
__global__ void k_weights(const float* __restrict__ d2, const float* __restrict__ lt,
                          float* __restrict__ w)
{
  int t = threadIdx.x;
  if (t < PL){
    float tau = log1pf(expf(lt[t]));
    float denom = (float)KS * tau;
    float lg[LL]; float mx = -1e30f;
    for (int l = 0; l < LL; l++){ lg[l] = -d2[t*LL+l]/denom; mx = fmaxf(mx, lg[l]); }
    float s = 0.f;
    for (int l = 0; l < LL; l++){ lg[l] = expf(lg[l]-mx); s += lg[l]; }
    for (int l = 0; l < LL; l++) w[t*LL+l] = lg[l]/s;
  }
}

// ---------------- mixing kernels ----------------
__global__ __launch_bounds__(256) void k_mix_tok(const float* __restrict__ tt,
                                                 const float* __restrict__ w,
                                                 float* __restrict__ out)
{
  __shared__ float sw[PL*LL];
  if (threadIdx.x < PL*LL) sw[threadIdx.x] = w[threadIdx.x];
  __syncthreads();
  const size_t N4 = (size_t)BB*SEQ*DT/4;
  const float4* t4 = (const float4*)tt;
  float4* o4 = (float4*)out;
  for (size_t i = (size_t)blockIdx.x*256 + threadIdx.x; i < N4; i += (size_t)gridDim.x*256){
    float4 a[PL];
#pragma unroll
    for (int p = 0; p < PL; p++){ a[p].x = 0; a[p].y = 0; a[p].z = 0; a[p].w = 0; }
    for (int l = 0; l < LL; l++){
      float4 v = t4[(size_t)l*N4 + i];
#pragma unroll
      for (int p = 0; p < PL; p++){
        float ww = sw[p*LL+l];
        a[p].x += ww*v.x; a[p].y += ww*v.y; a[p].z += ww*v.z; a[p].w += ww*v.w;
      }
    }
#pragma unroll
    for (int p = 0; p < PL; p++) o4[(size_t)p*N4 + i] = a[p];
  }
}

__global__ __launch_bounds__(256) void k_mix_attn(const float* __restrict__ at,
                                                  const float* __restrict__ w,
                                                  float* __restrict__ out)
{
  __shared__ float sw[PL*LL];
  if (threadIdx.x < PL*LL) sw[threadIdx.x] = w[threadIdx.x];
  __syncthreads();
  const size_t N4 = (size_t)BB*HEADS*SEQ*SEQ/4;
  const float4* t4 = (const float4*)at;
  float4* o4 = (float4*)out;
  for (size_t i = (size_t)blockIdx.x*256 + threadIdx.x; i < N4; i += (size_t)gridDim.x*256){
    float4 a[PL];
#pragma unroll
    for (int p = 0; p < PL; p++){ a[p].x = 0; a[p].y = 0; a[p].z = 0; a[p].w = 0; }
    for (int l = 0; l < LL; l++){
      float4 v = t4[(size_t)l*N4 + i];
#pragma unroll
      for (int p = 0; p < PL; p++){
        float ww = sw[p*LL+l];
        a[p].x += ww*v.x; a[p].y += ww*v.y; a[p].z += ww*v.z; a[p].w += ww*v.w;
      }
    }
#pragma unroll
    for (int p = 0; p < PL; p++) o4[(size_t)p*N4 + i] = a[p];
  }
}

// ---------------- host ----------------
extern "C" void kernel_launch(void* const* d_in, const int* in_sizes, int n_in,
                              void* d_out, int out_size, void* d_ws, size_t ws_size,
                              hipStream_t stream)
{
  const float* student = (const float*)d_in[0];
  const float* teacher = (const float*)d_in[1];
  const float* attns   = (const float*)d_in[2];
  const float* proj_s  = (const float*)d_in[3];
  const float* proj_t  = (const float*)d_in[4];
  const float* logtemp = (const float*)d_in[5];
  float* out = (float*)d_out;

  // ---- scratch layout (floats) ----
  const size_t o_Z   = 0;                          // 4,841,472  (4-layer Z chunk)
  const size_t o_C   = o_Z   + (size_t)4*MR*DS;    // 2,359,296
  const size_t o_Wa  = o_C   + (size_t)NMAT*DS*DS; // 884,736
  const size_t o_Wb  = o_Wa  + (size_t)NMAT*DS*PD;
  const size_t o_G   = o_Wb  + (size_t)NMAT*DS*PD; // 331,776
  const size_t o_R   = o_G   + (size_t)NMAT*PD*PD; // 169,344
  const size_t o_B   = o_R   + (size_t)NMAT*(PD*(PD+1)/2 + PD);
  const size_t o_Bh  = o_B   + (size_t)NMAT*PD*PD;
  const size_t o_bet = o_Bh  + (size_t)NMAT*PD*PD; // Bh now full rows (reflectors)
  const size_t o_de  = o_bet + (size_t)NMAT*PD;
  const size_t o_Y   = o_de  + (size_t)NMAT*2*PD;
  const size_t o_U   = o_Y   + (size_t)NMAT*PD*KS;
  const size_t o_M   = o_U   + (size_t)NMAT*DS*KS;
  const size_t o_mu  = o_M   + (size_t)48*KS*KS;
  const size_t o_u   = o_mu  + (size_t)NMAT*DS;
  const size_t o_sm  = o_u   + 16;
  const size_t TOTAL = o_sm + 96;
  const size_t NEED_BYTES = TOTAL*sizeof(float);

  bool ws_ok = (ws_size >= NEED_BYTES);
  float* base = ws_ok ? (float*)d_ws : (float*)d_out;  // d_out (158MB) as fallback scratch
  float* Zb  = base + o_Z;
  float* Cp  = base + o_C;
  float* Wa  = base + o_Wa;
  float* Wb  = base + o_Wb;
  float* Gp_ = base + o_G;
  float* Rp_ = base + o_R;
  float* Bp_ = base + o_B;
  float* Bh_ = base + o_Bh;
  float* bet_= base + o_bet;
  float* de_ = base + o_de;
  float* Y_  = base + o_Y;
  float* U_  = base + o_U;
  float* Mp_ = base + o_M;
  float* mu_ = base + o_mu;
  float* up_ = base + o_u;
  // d2/weights must survive the mixing kernels -> keep them in d_ws always
  float* d2_ = ws_ok ? (base + o_sm) : (float*)d_ws;
  float* w_  = d2_ + 48;

  hipMemsetAsync(mu_, 0, (size_t)NMAT*DS*sizeof(float), stream);
  hipMemsetAsync(Cp, 0, (size_t)NMAT*DS*DS*sizeof(float), stream);

  // ---- Z / mean / covariance, 4 chunks of 4 matrices ----
  for (int ch = 0; ch < 4; ch++){
    const float* src; const float* proj; int Kdim; int mat0;
    if (ch < 3){ src = teacher + (size_t)ch*4*MR*DT; proj = proj_t; Kdim = DT; mat0 = ch*4; }
    else       { src = student;                      proj = proj_s; Kdim = DS; mat0 = 12; }
    k_zgemm<<<dim3(3,197), 256, 0, stream>>>(src, proj, Zb, Kdim);
    k_mu<<<788, 256, 0, stream>>>(Zb, mu_, mat0);
    k_cov<<<dim3(3,6,32), 256, 0, stream>>>(Zb, Cp, mat0);
  }
  k_cov_epi<<<9216, 256, 0, stream>>>(Cp, mu_);
  k_lmax<<<NMAT, 384, 0, stream>>>(Cp, up_);

  // ---- Chebyshev-filtered subspace iteration ----
  k_omega<<<(NMAT*DS*PD)/256, 256, 0, stream>>>(Wa);
  const dim3 gch(3, 6, NMAT);
  const i64 wS = (i64)DS*PD, cS = (i64)DS*DS;

  // round 1: T0 = Wa
  k_cheb<<<gch,256,0,stream>>>(Cp, DS, cS, Wa, PD, wS, Wb, wS, nullptr, Wa, up_, DS, PD, 1);
  {
    float* Tprev = Wa; float* Tcur = Wb;
    for (int j = 2; j <= 7; j++){
      k_cheb<<<gch,256,0,stream>>>(Cp, DS, cS, Tcur, PD, wS, Tprev, wS, Tcur, Tprev, up_, DS, PD, 2);
      float* tmp = Tprev; Tprev = Tcur; Tcur = tmp;
    }
  } // T7 -> Wb
  const i64 rS = (i64)(PD*(PD+1)/2 + PD);
  auto cholqr = [&](float* W, float ridge){
    k_tn<<<dim3(3,3,NMAT),256,0,stream>>>(W, wS, W, wS, Gp_, (i64)PD*PD, PD, DS, 0);
    k_chol<<<NMAT,256,0,stream>>>(Gp_, (i64)PD*PD, Rp_, rS, PD, ridge);
    k_trisolve<<<(NMAT*DS)/64,64,0,stream>>>(W, wS, DS, Rp_, rS, PD);
  };
  cholqr(Wb, 3e-6f);

  // round 2: T0 = Wb
  k_cheb<<<gch,256,0,stream>>>(Cp, DS, cS, Wb, PD, wS, Wa, wS, nullptr, Wb, up_, DS, PD, 1);
  {
    float* Tprev = Wb; float* Tcur = Wa;
    for (int j = 2; j <= 7; j++){
      k_cheb<<<gch,256,0,stream>>>(Cp, DS, cS, Tcur, PD, wS, Tprev, wS, Tcur, Tprev, up_, DS, PD, 2);
      float* tmp = Tprev; Tprev = Tcur; Tcur = tmp;
    }
  } // T7 -> Wa
  cholqr(Wa, 3e-6f);
  cholqr(Wa, 1e-7f);   // Q in Wa

  // ---- Rayleigh-Ritz: B = Q^T C Q ----
  k_cheb<<<gch,256,0,stream>>>(Cp, DS, cS, Wa, PD, wS, Wb, wS, nullptr, nullptr, up_, DS, PD, 0); // Wb = C Q
  k_tn<<<dim3(3,3,NMAT),256,0,stream>>>(Wa, wS, Wb, wS, Bp_, (i64)PD*PD, PD, DS, 0);

  {
    const size_t tridiag_lds = (size_t)(PD*TLDA + 4*PD + 8) * sizeof(float); // ~87.6 KB
    k_tridiagB<<<NMAT,256,tridiag_lds,stream>>>(Bp_, Bh_, bet_, de_);
  }
  k_invit<<<NMAT,256,0,stream>>>(de_, Y_);
  k_backxf<<<NMAT,256,0,stream>>>(Bh_, bet_, Y_);

  // CholQR safety on Y (orthonormal Ritz basis)
  const i64 r96S = (i64)(KS*(KS+1)/2 + KS);
  k_tn<<<dim3(2,2,NMAT),256,0,stream>>>(Y_, (i64)PD*KS, Y_, (i64)PD*KS, Gp_, (i64)KS*KS, KS, PD, 0);
  k_chol<<<NMAT,256,0,stream>>>(Gp_, (i64)KS*KS, Rp_, r96S, KS, 1e-6f);
  k_trisolve<<<(NMAT*PD)/64,64,0,stream>>>(Y_, (i64)PD*KS, PD, Rp_, r96S, KS);

  // U = Q Y  [384 x 96] per matrix
  k_cheb<<<dim3(2,6,NMAT),256,0,stream>>>(Wa, PD, wS, Y_, KS, (i64)PD*KS, U_, (i64)DS*KS,
                                          nullptr, nullptr, up_, PD, KS, 0);
  // M_pl = U_s^T U_t  (48 pairs)
  k_tn<<<dim3(2,2,48),256,0,stream>>>(U_, (i64)DS*KS, U_, (i64)DS*KS, Mp_, (i64)KS*KS, KS, DS, 1);
  // Gram of M (48 x [96x96]) into Wa (free after U), then eigen/angles
  k_tn<<<dim3(2,2,48),256,0,stream>>>(Mp_, (i64)KS*KS, Mp_, (i64)KS*KS, Wa, (i64)KS*KS, KS, KS, 0);
  k_sigma<<<48,256,0,stream>>>(Wa, d2_);
  k_weights<<<1,64,0,stream>>>(d2_, logtemp, w_);

  // ---- mixing (reads only inputs + w_, so scratch-in-d_out fallback is safe) ----
  k_mix_tok<<<2364,256,0,stream>>>(teacher, w_, out);
  k_mix_attn<<<4096,256,0,stream>>>(attns, w_, out + (size_t)PL*BB*SEQ*DT);
}